// Round 15
// baseline (86.671 us; speedup 1.0000x reference)
//
#include <hip/hip_runtime.h>

typedef short bf16x8 __attribute__((ext_vector_type(8)));
typedef float f32x4  __attribute__((ext_vector_type(4)));
typedef unsigned short ushort_t;

#define HID 32
#define CC  64
#define TT  8
#define NN  1024
#define BB  4
#define KTOT 8192
#define NKC_P 32               // k-chunks for k_psum; KCHUNK_P=256
#define KCHUNK_P (KTOT/NKC_P)  // 256

// f32 -> bf16 (RNE)
__device__ __forceinline__ ushort_t f2b(float x) {
    unsigned int u = __float_as_uint(x);
    return (ushort_t)((u + 0x7fffu + ((u >> 16) & 1u)) >> 16);
}
__device__ __forceinline__ float b2f(ushort_t u) {
    return __uint_as_float((unsigned int)u << 16);
}

// --- K1 fused: blocks 0..255 -> hkT planes + hkDB;  blocks 256..271 -> hq hi/lo ---
__global__ __launch_bounds__(256) void k_pre(const float* __restrict__ H,
                                             const float* __restrict__ h,
                                             const float* __restrict__ wq,
                                             const float* __restrict__ wkv,
                                             ushort_t* __restrict__ hqHI,
                                             ushort_t* __restrict__ hqLO,
                                             ushort_t* __restrict__ hkTH0,
                                             ushort_t* __restrict__ hkTH1,
                                             ushort_t* __restrict__ hkTL0,
                                             ushort_t* __restrict__ hkTL1,
                                             ushort_t* __restrict__ hkDB) {
    int bx = blockIdx.x;
    if (bx < 256) {
        int gid = bx * 256 + threadIdx.x;          // 0..65535
        int dg = gid >> 15;                        // block-uniform d-half
        int rest = gid & 32767;
        int b = rest >> 13, tn = rest & 8191;
        int d0 = dg << 4;
        float acc[16];
#pragma unroll
        for (int d = 0; d < 16; d++) acc[d] = 0.f;
        const float* Hb = H + (size_t)(b * CC) * KTOT + tn;
        const float* wb = wkv + d0 * CC;
#pragma unroll 8
        for (int c = 0; c < CC; c++) {
            float v = Hb[(size_t)c * KTOT];        // coalesced
#pragma unroll
            for (int d = 0; d < 16; d++) acc[d] += wb[d * CC + c] * v;  // uniform -> s_load
        }
        ushort_t thi[16], tlo[16];
#pragma unroll
        for (int d = 0; d < 16; d++) {
            ushort_t hi = f2b(acc[d]);
            thi[d] = hi;
            tlo[d] = f2b(acc[d] - b2f(hi));
        }
        size_t po = ((size_t)b * KTOT + tn) * 16;
        bf16x8* ohi = (bf16x8*)((dg ? hkTH1 : hkTH0) + po);
        bf16x8* olo = (bf16x8*)((dg ? hkTL1 : hkTL0) + po);
#pragma unroll
        for (int v8 = 0; v8 < 2; v8++) {
            bf16x8 a, l;
#pragma unroll
            for (int j = 0; j < 8; j++) { a[j] = (short)thi[v8*8+j]; l[j] = (short)tlo[v8*8+j]; }
            ohi[v8] = a; olo[v8] = l;
        }
#pragma unroll
        for (int d = 0; d < 16; d++)
            hkDB[((size_t)(b * HID) + d0 + d) * KTOT + tn] = thi[d];   // coalesced per d
    } else {
        int gid = (bx - 256) * 256 + threadIdx.x;  // 0..4095
        int b = gid >> 10;
        float acc[HID];
#pragma unroll
        for (int d = 0; d < HID; d++) acc[d] = 0.f;
        const float* hb = h + (size_t)(b * CC) * NN + (gid & 1023);
#pragma unroll 4
        for (int c = 0; c < CC; c++) {
            float v = hb[c * NN];                  // coalesced
#pragma unroll
            for (int d = 0; d < HID; d++) acc[d] += wq[d * CC + c] * v;
        }
        bf16x8* ohi = (bf16x8*)(hqHI + (size_t)gid * HID);
        bf16x8* olo = (bf16x8*)(hqLO + (size_t)gid * HID);
#pragma unroll
        for (int v8 = 0; v8 < 4; v8++) {
            bf16x8 thi, tlo;
#pragma unroll
            for (int j = 0; j < 8; j++) {
                float x = acc[v8 * 8 + j];
                ushort_t hi = f2b(x);
                thi[j] = (short)hi;
                tlo[j] = (short)f2b(x - b2f(hi));
            }
            ohi[v8] = thi; olo[v8] = tlo;
        }
    }
}

// ---- Denominators: psum[b][kc][m] = sum over chunk of exp(bf16 score) ----
__global__ __launch_bounds__(512, 8) void k_psum(const ushort_t* __restrict__ hqHI,
                                                 const ushort_t* __restrict__ hkTH0,
                                                 const ushort_t* __restrict__ hkTH1,
                                                 float* __restrict__ psum) {
    int bx = blockIdx.x;                           // 1024: b(4) x mt(8) x kc(32)
    int b = bx >> 8, mt = (bx >> 5) & 7, kc = bx & 31;
    int wave = threadIdx.x >> 6, lane = threadIdx.x & 63;
    int g = lane >> 4, c = lane & 15;
    int m = mt * 128 + wave * 16 + c;
    int t = kc >> 2;
    int nb0 = (kc & 3) << 8;                       // chunk covers n in [nb0, nb0+256)

    size_t bqo = ((size_t)b * KTOT + t * NN + m) * 16 + (g & 1) * 8;
    bf16x8 bqh = *(const bf16x8*)(((g >> 1) ? hkTH1 : hkTH0) + bqo);

    const ushort_t* qhi = hqHI + ((size_t)(b << 10)) * HID;

    float csum0 = 0.f, csum1 = 0.f;
    for (int s16 = 0; s16 < KCHUNK_P / 16; s16 += 2) {  // 8 iters, 2 tiles each
        int nbA = nb0 + s16 * 16;
        int nbB = nbA + 16;
        bf16x8 ahA = *(const bf16x8*)(qhi + (size_t)(nbA + c) * HID + 8 * g);
        bf16x8 ahB = *(const bf16x8*)(qhi + (size_t)(nbB + c) * HID + 8 * g);
        f32x4 svA = __builtin_amdgcn_mfma_f32_16x16x32_bf16(ahA, bqh, (f32x4){0.f,0.f,0.f,0.f}, 0, 0, 0);
        f32x4 svB = __builtin_amdgcn_mfma_f32_16x16x32_bf16(ahB, bqh, (f32x4){0.f,0.f,0.f,0.f}, 0, 0, 0);
        int nrowA = nbA + 4 * g;                   // D row = query n
        int nrowB = nbB + 4 * g;
#pragma unroll
        for (int r = 0; r < 4; r++) {
            float xA = (nrowA + r == m) ? 0.f : svA[r];
            float xB = (nrowB + r == m) ? 0.f : svB[r];
            csum0 += __expf(xA);
            csum1 += __expf(xB);
        }
    }
    float csum = csum0 + csum1;
    csum += __shfl_xor(csum, 16);
    csum += __shfl_xor(csum, 32);
    if (lane < 16)
        psum[(((size_t)(b * NKC_P + kc)) << 10) + mt * 128 + wave * 16 + lane] = csum;
}

// ---- Main: single sweep, FULL-LINE att writes. 256 blocks = b(4) x mg(32 x 32-col) x kh(2 n-half).
//      16 waves = t(8) x m-half(2). Block writes hvp[kh] partial (cross-block k-split). ----
__global__ __launch_bounds__(1024) void k_main(const ushort_t* __restrict__ hqHI,
                                               const ushort_t* __restrict__ hqLO,
                                               const ushort_t* __restrict__ hkTH0,
                                               const ushort_t* __restrict__ hkTH1,
                                               const ushort_t* __restrict__ hkTL0,
                                               const ushort_t* __restrict__ hkTL1,
                                               const ushort_t* __restrict__ hkDB,
                                               const float* __restrict__ psum,
                                               float* __restrict__ att,
                                               float* __restrict__ hvp) {
    int bx = blockIdx.x;
    int logical = ((bx & 7) << 5) | (bx >> 3);     // XCD-bijective swizzle (256 = 8 x 32)
    int b = logical >> 6;
    int r6 = logical & 63;
    int mg = r6 >> 1, kh = r6 & 1;
    int mb32 = mg << 5;                            // block's 32-col (128 B) att stripe
    int tid = threadIdx.x;
    int wave = tid >> 6, lane = tid & 63;
    int g = lane >> 4, c = lane & 15;
    int t = wave >> 1, mh = wave & 1;
    int mbw = mb32 + (mh << 4);                    // wave's 16-col m-tile
    int nh = kh << 9;                              // n-half base

    __shared__ float hvred[16][16][32];            // [wave][m-local][d]
    __shared__ __align__(16) ushort_t PT[16][16][40];

    // denominators for this lane's 4 m's (m = mbw + 4g + r)
    f32x4 gs = {0.f, 0.f, 0.f, 0.f};
#pragma unroll
    for (int j = 0; j < NKC_P; j++)
        gs += *(const f32x4*)(psum + (((size_t)(b * NKC_P + j)) << 10) + mbw + 4 * g);
    f32x4 vinv;
#pragma unroll
    for (int r = 0; r < 4; r++) vinv[r] = 1.0f / gs[r];

    // A frag (loop-invariant): key[mbw+c][d] at this t, hi/lo
    size_t ako = ((size_t)b * KTOT + t * NN + (mbw + c)) * 16 + (g & 1) * 8;
    bf16x8 akh = *(const bf16x8*)(((g >> 1) ? hkTH1 : hkTH0) + ako);
    bf16x8 akl = *(const bf16x8*)(((g >> 1) ? hkTL1 : hkTL0) + ako);

    const ushort_t* qhi = hqHI + ((size_t)(b << 10)) * HID;
    const ushort_t* qlo = hqLO + ((size_t)(b << 10)) * HID;
    const ushort_t* vb0 = hkDB + (size_t)(b * HID + c) * KTOT;
    const ushort_t* vb1 = hkDB + (size_t)(b * HID + 16 + c) * KTOT;
    float* attb = att + (size_t)b * KTOT * NN;
    ushort_t (*pt)[40] = PT[wave];

    f32x4 acc0 = {0.f,0.f,0.f,0.f}, acc1 = {0.f,0.f,0.f,0.f};

    for (int ks = 0; ks < 16; ks++) {              // 16 iters, 32 k each
        int k0 = t * NN + nh + ks * 32;
#pragma unroll
        for (int half = 0; half < 2; half++) {
            int nb = nh + ks * 32 + half * 16;
            size_t qo = (size_t)(nb + c) * HID + 8 * g;
            bf16x8 qh = *(const bf16x8*)(qhi + qo);
            bf16x8 ql = *(const bf16x8*)(qlo + qo);
            f32x4 sv = __builtin_amdgcn_mfma_f32_16x16x32_bf16(akh, ql, (f32x4){0.f,0.f,0.f,0.f}, 0, 0, 0);
            sv = __builtin_amdgcn_mfma_f32_16x16x32_bf16(akl, qh, sv, 0, 0, 0);
            sv = __builtin_amdgcn_mfma_f32_16x16x32_bf16(akh, qh, sv, 0, 0, 0);
            int n = nb + c;                        // this lane's att row
            float e0 = __expf((n == mbw + 4 * g + 0) ? 0.f : sv[0]) * vinv[0];
            float e1 = __expf((n == mbw + 4 * g + 1) ? 0.f : sv[1]) * vinv[1];
            float e2 = __expf((n == mbw + 4 * g + 2) ? 0.f : sv[2]) * vinv[2];
            float e3 = __expf((n == mbw + 4 * g + 3) ? 0.f : sv[3]) * vinv[3];
            f32x4 ev; ev[0] = e0; ev[1] = e1; ev[2] = e2; ev[3] = e3;
            *(f32x4*)(attb + (size_t)(t * NN + n) * NN + mbw + 4 * g) = ev;   // 16B/lane
            int kl = half * 16 + c;
            pt[4 * g + 0][kl] = f2b(e0);
            pt[4 * g + 1][kl] = f2b(e1);
            pt[4 * g + 2][kl] = f2b(e2);
            pt[4 * g + 3][kl] = f2b(e3);
        }
        // GEMM2 (normalized): hv[m,d] += sum_k P[m,k] * V[k,d]
        bf16x8 pa = *(const bf16x8*)&pt[c][8 * g];        // A2[m=c][k=8g+j]
        bf16x8 v0 = *(const bf16x8*)(vb0 + k0 + 8 * g);   // B2[k][d=c]
        bf16x8 v1 = *(const bf16x8*)(vb1 + k0 + 8 * g);   // B2[k][d=16+c]
        acc0 = __builtin_amdgcn_mfma_f32_16x16x32_bf16(pa, v0, acc0, 0, 0, 0);
        acc1 = __builtin_amdgcn_mfma_f32_16x16x32_bf16(pa, v1, acc1, 0, 0, 0);
    }

    // ---- reduce hv over the 8 same-m-half waves; write hvp[kh][b][m][d] ----
#pragma unroll
    for (int r = 0; r < 4; r++) {
        hvred[wave][4 * g + r][c]      = acc0[r];
        hvred[wave][4 * g + r][16 + c] = acc1[r];
    }
    __syncthreads();
    {
        int m32 = tid >> 5, d = tid & 31;          // 1024 threads = 32 m x 32 d
        int mhh = m32 >> 4, ml = m32 & 15;
        float s = 0.f;
#pragma unroll
        for (int tt = 0; tt < 8; tt++) s += hvred[tt * 2 + mhh][ml][d];
        hvp[(((size_t)(kh * 4 + b) << 10) + mb32 + m32) * HID + d] = s;
    }
}

// ---- out0[b,c,m] = h[b,c,m] + sum_d w_o[c,d] * (hvp[0]+hvp[1]) ----
__global__ __launch_bounds__(512) void k_out(const float* __restrict__ h,
                                             const float* __restrict__ wo,
                                             const float* __restrict__ hvp,
                                             float* __restrict__ out0) {
    int bx = blockIdx.x;                           // 256: b(4) x mt(64)
    int b = bx >> 6, mt = bx & 63;
    int m0 = mt * 16;
    int tid = threadIdx.x;
    __shared__ float hvL[16][33];
    {
        int mm = tid >> 5, d = tid & 31;           // one value per thread
        size_t i0 = ((size_t)(b << 10) + m0 + mm) * HID + d;
        hvL[mm][d] = hvp[i0] + hvp[((size_t)4 << 15) + i0];
    }
    __syncthreads();
#pragma unroll
    for (int i0 = 0; i0 < 2; i0++) {
        int i = i0 * 512 + tid;
        int c = i >> 4, mm = i & 15;
        float v = h[(size_t)(b * CC + c) * NN + m0 + mm];
#pragma unroll
        for (int d = 0; d < HID; d++) v += wo[c * HID + d] * hvL[mm][d];
        out0[(size_t)(b * CC + c) * NN + m0 + mm] = v;
    }
}

extern "C" void kernel_launch(void* const* d_in, const int* in_sizes, int n_in,
                              void* d_out, int out_size, void* d_ws, size_t ws_size,
                              hipStream_t stream) {
    const float* H   = (const float*)d_in[0];
    const float* h   = (const float*)d_in[1];
    const float* wq  = (const float*)d_in[2];
    const float* wkv = (const float*)d_in[3];
    const float* wo  = (const float*)d_in[4];

    float* out0 = (float*)d_out;                       // [4,64,32,32]
    float* att  = out0 + (size_t)BB * CC * NN;         // [4,8192,1024]

    ushort_t* hqHI  = (ushort_t*)d_ws;                 // 131072
    ushort_t* hqLO  = hqHI  + 131072;                  // 131072
    ushort_t* hkTH0 = hqLO  + 131072;                  // 524288
    ushort_t* hkTH1 = hkTH0 + 524288;                  // 524288
    ushort_t* hkTL0 = hkTH1 + 524288;                  // 524288
    ushort_t* hkTL1 = hkTL0 + 524288;                  // 524288
    ushort_t* hkDB  = hkTL1 + 524288;                  // 1048576
    float* psum = (float*)(hkDB + 1048576);            // 131072
    float* hvp  = psum + 131072;                       // 262144 f32 (~9 MB total)

    k_pre <<<272,  256,  0, stream>>>(H, h, wq, wkv, hqHI, hqLO,
                                      hkTH0, hkTH1, hkTL0, hkTL1, hkDB);
    k_psum<<<1024, 512,  0, stream>>>(hqHI, hkTH0, hkTH1, psum);
    k_main<<<256,  1024, 0, stream>>>(hqHI, hqLO, hkTH0, hkTH1, hkTL0, hkTL1, hkDB,
                                      psum, att, hvp);
    k_out <<<256,  512,  0, stream>>>(h, wo, hvp, out0);
}

// Round 16
// 83.164 us; speedup vs baseline: 1.0422x; 1.0422x over previous
//
#include <hip/hip_runtime.h>

typedef short bf16x8 __attribute__((ext_vector_type(8)));
typedef float f32x4  __attribute__((ext_vector_type(4)));
typedef unsigned short ushort_t;

#define HID 32
#define CC  64
#define TT  8
#define NN  1024
#define BB  4
#define KTOT 8192

// f32 -> bf16 (RNE)
__device__ __forceinline__ ushort_t f2b(float x) {
    unsigned int u = __float_as_uint(x);
    return (ushort_t)((u + 0x7fffu + ((u >> 16) & 1u)) >> 16);
}
__device__ __forceinline__ float b2f(ushort_t u) {
    return __uint_as_float((unsigned int)u << 16);
}

// --- K1 fused: blocks 0..255 -> hkT planes + hkDB;  blocks 256..271 -> hq hi/lo ---
__global__ __launch_bounds__(256) void k_pre(const float* __restrict__ H,
                                             const float* __restrict__ h,
                                             const float* __restrict__ wq,
                                             const float* __restrict__ wkv,
                                             ushort_t* __restrict__ hqHI,
                                             ushort_t* __restrict__ hqLO,
                                             ushort_t* __restrict__ hkTH0,
                                             ushort_t* __restrict__ hkTH1,
                                             ushort_t* __restrict__ hkTL0,
                                             ushort_t* __restrict__ hkTL1,
                                             ushort_t* __restrict__ hkDB) {
    int bx = blockIdx.x;
    if (bx < 256) {
        int gid = bx * 256 + threadIdx.x;          // 0..65535
        int dg = gid >> 15;                        // block-uniform d-half
        int rest = gid & 32767;
        int b = rest >> 13, tn = rest & 8191;
        int d0 = dg << 4;
        float acc[16];
#pragma unroll
        for (int d = 0; d < 16; d++) acc[d] = 0.f;
        const float* Hb = H + (size_t)(b * CC) * KTOT + tn;
        const float* wb = wkv + d0 * CC;
#pragma unroll 8
        for (int c = 0; c < CC; c++) {
            float v = Hb[(size_t)c * KTOT];        // coalesced
#pragma unroll
            for (int d = 0; d < 16; d++) acc[d] += wb[d * CC + c] * v;  // uniform -> s_load
        }
        ushort_t thi[16], tlo[16];
#pragma unroll
        for (int d = 0; d < 16; d++) {
            ushort_t hi = f2b(acc[d]);
            thi[d] = hi;
            tlo[d] = f2b(acc[d] - b2f(hi));
        }
        size_t po = ((size_t)b * KTOT + tn) * 16;
        bf16x8* ohi = (bf16x8*)((dg ? hkTH1 : hkTH0) + po);
        bf16x8* olo = (bf16x8*)((dg ? hkTL1 : hkTL0) + po);
#pragma unroll
        for (int v8 = 0; v8 < 2; v8++) {
            bf16x8 a, l;
#pragma unroll
            for (int j = 0; j < 8; j++) { a[j] = (short)thi[v8*8+j]; l[j] = (short)tlo[v8*8+j]; }
            ohi[v8] = a; olo[v8] = l;
        }
#pragma unroll
        for (int d = 0; d < 16; d++)
            hkDB[((size_t)(b * HID) + d0 + d) * KTOT + tn] = thi[d];   // coalesced per d
    } else {
        int gid = (bx - 256) * 256 + threadIdx.x;  // 0..4095
        int b = gid >> 10;
        float acc[HID];
#pragma unroll
        for (int d = 0; d < HID; d++) acc[d] = 0.f;
        const float* hb = h + (size_t)(b * CC) * NN + (gid & 1023);
#pragma unroll 4
        for (int c = 0; c < CC; c++) {
            float v = hb[c * NN];                  // coalesced
#pragma unroll
            for (int d = 0; d < HID; d++) acc[d] += wq[d * CC + c] * v;
        }
        bf16x8* ohi = (bf16x8*)(hqHI + (size_t)gid * HID);
        bf16x8* olo = (bf16x8*)(hqLO + (size_t)gid * HID);
#pragma unroll
        for (int v8 = 0; v8 < 4; v8++) {
            bf16x8 thi, tlo;
#pragma unroll
            for (int j = 0; j < 8; j++) {
                float x = acc[v8 * 8 + j];
                ushort_t hi = f2b(x);
                thi[j] = (short)hi;
                tlo[j] = (short)f2b(x - b2f(hi));
            }
            ohi[v8] = thi; olo[v8] = tlo;
        }
    }
}

// ---- K2: denom (bf16 scores) + unnormalized GEMM2 -> hv -> out0; writes inv[b][m].
// 256 blocks (XCD-swizzled) = b(4) x mt(64); 16 waves; wave w: t=w>>1, n-half=(w&1)*512.
__global__ __launch_bounds__(1024) void k_hv(const ushort_t* __restrict__ hqHI,
                                             const ushort_t* __restrict__ hkTH0,
                                             const ushort_t* __restrict__ hkTH1,
                                             const ushort_t* __restrict__ hkDB,
                                             const float* __restrict__ h,
                                             const float* __restrict__ wo,
                                             float* __restrict__ inv,
                                             float* __restrict__ out0) {
    int bx = blockIdx.x;
    int logical = ((bx & 7) << 5) | (bx >> 3);     // XCD-bijective swizzle (256 = 8 x 32)
    int b = logical >> 6, mt = logical & 63;
    int mb = mt << 4;                              // 16-wide m-tile
    int tid = threadIdx.x;
    int wave = tid >> 6, lane = tid & 63;
    int g = lane >> 4, c = lane & 15;
    int t = wave >> 1;
    int nh = (wave & 1) << 9;                      // n-half base

    __shared__ float csred[16][16];                // [wave][m-local]
    __shared__ float hvred[16][16][32];            // [wave][m-local][d]
    __shared__ float hvL[16][33];
    __shared__ __align__(16) ushort_t PT[16][16][40];

    // A frag (loop-invariant): key[mb+c][d] at this t (hi only — denominator precision)
    size_t ako = ((size_t)b * KTOT + t * NN + (mb + c)) * 16 + (g & 1) * 8;
    bf16x8 akh = *(const bf16x8*)(((g >> 1) ? hkTH1 : hkTH0) + ako);

    const ushort_t* qhi = hqHI + ((size_t)(b << 10)) * HID;
    const ushort_t* vb0 = hkDB + (size_t)(b * HID + c) * KTOT;
    const ushort_t* vb1 = hkDB + (size_t)(b * HID + 16 + c) * KTOT;
    ushort_t (*pt)[40] = PT[wave];

    f32x4 cs = {0.f, 0.f, 0.f, 0.f};
    f32x4 acc0 = {0.f,0.f,0.f,0.f}, acc1 = {0.f,0.f,0.f,0.f};
    for (int ks = 0; ks < 16; ks++) {              // 16 iters, 32 k each
        int k0 = t * NN + nh + ks * 32;
#pragma unroll
        for (int half = 0; half < 2; half++) {
            int nb = nh + ks * 32 + half * 16;
            size_t qo = (size_t)(nb + c) * HID + 8 * g;
            bf16x8 qh = *(const bf16x8*)(qhi + qo);
            f32x4 sv = __builtin_amdgcn_mfma_f32_16x16x32_bf16(akh, qh, (f32x4){0.f,0.f,0.f,0.f}, 0, 0, 0);
            int n = nb + c;
            float e0 = __expf((n == mb + 4 * g + 0) ? 0.f : sv[0]);
            float e1 = __expf((n == mb + 4 * g + 1) ? 0.f : sv[1]);
            float e2 = __expf((n == mb + 4 * g + 2) ? 0.f : sv[2]);
            float e3 = __expf((n == mb + 4 * g + 3) ? 0.f : sv[3]);
            cs[0] += e0; cs[1] += e1; cs[2] += e2; cs[3] += e3;
            int kl = half * 16 + c;
            pt[4 * g + 0][kl] = f2b(e0);
            pt[4 * g + 1][kl] = f2b(e1);
            pt[4 * g + 2][kl] = f2b(e2);
            pt[4 * g + 3][kl] = f2b(e3);
        }
        bf16x8 pa = *(const bf16x8*)&pt[c][8 * g];        // A2[m=c][k=8g+j]
        bf16x8 v0 = *(const bf16x8*)(vb0 + k0 + 8 * g);   // B2[k][d=c]
        bf16x8 v1 = *(const bf16x8*)(vb1 + k0 + 8 * g);   // B2[k][d=16+c]
        acc0 = __builtin_amdgcn_mfma_f32_16x16x32_bf16(pa, v0, acc0, 0, 0, 0);
        acc1 = __builtin_amdgcn_mfma_f32_16x16x32_bf16(pa, v1, acc1, 0, 0, 0);
    }
    // reduce csum over the 16 c-lanes
#pragma unroll
    for (int off = 1; off <= 8; off <<= 1) {
        cs[0] += __shfl_xor(cs[0], off, 64);
        cs[1] += __shfl_xor(cs[1], off, 64);
        cs[2] += __shfl_xor(cs[2], off, 64);
        cs[3] += __shfl_xor(cs[3], off, 64);
    }
    if (c == 0) *(f32x4*)&csred[wave][4 * g] = cs;
    __syncthreads();
    f32x4 gs = {0.f, 0.f, 0.f, 0.f};
#pragma unroll
    for (int w = 0; w < 16; w++)
        gs += *(const f32x4*)&csred[w][4 * g];
    f32x4 vinv;
#pragma unroll
    for (int r = 0; r < 4; r++) vinv[r] = 1.0f / gs[r];
    if (wave == 0 && c == 0)
        *(f32x4*)(inv + (b << 10) + mb + 4 * g) = vinv;    // publish for k_att

    // scale hv partials and reduce over waves
#pragma unroll
    for (int r = 0; r < 4; r++) {
        hvred[wave][4 * g + r][c]      = acc0[r] * vinv[r];
        hvred[wave][4 * g + r][16 + c] = acc1[r] * vinv[r];
    }
    __syncthreads();
    if (tid < 512) {
        int m = tid >> 5, d = tid & 31;
        float s = 0.f;
#pragma unroll
        for (int w = 0; w < 16; w++) s += hvred[w][m][d];
        hvL[m][d] = s;
    }
    __syncthreads();
    {
        int cc = tid >> 4, mm = tid & 15;          // 1024 threads = 64 c x 16 m
        float v = h[(size_t)(b * CC + cc) * NN + mb + mm];
#pragma unroll
        for (int d = 0; d < HID; d++) v += wo[cc * HID + d] * hvL[mm][d];
        out0[(size_t)(b * CC + cc) * NN + mb + mm] = v;
    }
}

// ---- K3: att writer with SEQUENTIAL per-block streams.
// 256 blocks = b(4) x t(8) x ng(8 x 128-row chunks); 16 waves x 64 m-cols (4 key frags).
// Per n-tile the block writes 16 complete 4KB att rows; block region is contiguous 512KB. ----
__global__ __launch_bounds__(1024) void k_att(const ushort_t* __restrict__ hqHI,
                                              const ushort_t* __restrict__ hqLO,
                                              const ushort_t* __restrict__ hkTH0,
                                              const ushort_t* __restrict__ hkTH1,
                                              const ushort_t* __restrict__ hkTL0,
                                              const ushort_t* __restrict__ hkTL1,
                                              const float* __restrict__ inv,
                                              float* __restrict__ att) {
    int bx = blockIdx.x;                           // b(4) x t(8) x ng(8)
    int b = bx >> 6, t = (bx >> 3) & 7, ng = bx & 7;
    int tid = threadIdx.x;
    int wave = tid >> 6, lane = tid & 63;
    int g = lane >> 4, c = lane & 15;
    int mf = wave << 6;                            // wave's 64-col m base

    // 4 key frags (hi/lo) + 4 vinv quads — loop-invariant
    bf16x8 akh[4], akl[4];
    f32x4 vinv[4];
#pragma unroll
    for (int f = 0; f < 4; f++) {
        size_t ako = ((size_t)b * KTOT + t * NN + (mf + 16 * f + c)) * 16 + (g & 1) * 8;
        akh[f] = *(const bf16x8*)(((g >> 1) ? hkTH1 : hkTH0) + ako);
        akl[f] = *(const bf16x8*)(((g >> 1) ? hkTL1 : hkTL0) + ako);
        vinv[f] = *(const f32x4*)(inv + (b << 10) + mf + 16 * f + 4 * g);
    }

    const ushort_t* qhi = hqHI + ((size_t)(b << 10)) * HID;
    const ushort_t* qlo = hqLO + ((size_t)(b << 10)) * HID;
    float* attb = att + (size_t)b * KTOT * NN;

    for (int ks = 0; ks < 8; ks++) {               // 8 n-tiles of 16 rows
        int nb = ng * 128 + ks * 16;
        size_t qo = (size_t)(nb + c) * HID + 8 * g;
        bf16x8 qh = *(const bf16x8*)(qhi + qo);
        bf16x8 ql = *(const bf16x8*)(qlo + qo);
        int n = nb + c;                            // this lane's att row
        float* rowp = attb + (size_t)(t * NN + n) * NN;
#pragma unroll
        for (int f = 0; f < 4; f++) {
            f32x4 sv = __builtin_amdgcn_mfma_f32_16x16x32_bf16(akh[f], ql, (f32x4){0.f,0.f,0.f,0.f}, 0, 0, 0);
            sv = __builtin_amdgcn_mfma_f32_16x16x32_bf16(akl[f], qh, sv, 0, 0, 0);
            sv = __builtin_amdgcn_mfma_f32_16x16x32_bf16(akh[f], qh, sv, 0, 0, 0);
            int mrow = mf + 16 * f + 4 * g;
            f32x4 ev;
            ev[0] = __expf((n == mrow + 0) ? 0.f : sv[0]) * vinv[f][0];
            ev[1] = __expf((n == mrow + 1) ? 0.f : sv[1]) * vinv[f][1];
            ev[2] = __expf((n == mrow + 2) ? 0.f : sv[2]) * vinv[f][2];
            ev[3] = __expf((n == mrow + 3) ? 0.f : sv[3]) * vinv[f][3];
            *(f32x4*)(rowp + mrow) = ev;           // 16B/lane; block rows fully covered
        }
    }
}

extern "C" void kernel_launch(void* const* d_in, const int* in_sizes, int n_in,
                              void* d_out, int out_size, void* d_ws, size_t ws_size,
                              hipStream_t stream) {
    const float* H   = (const float*)d_in[0];
    const float* h   = (const float*)d_in[1];
    const float* wq  = (const float*)d_in[2];
    const float* wkv = (const float*)d_in[3];
    const float* wo  = (const float*)d_in[4];

    float* out0 = (float*)d_out;                       // [4,64,32,32]
    float* att  = out0 + (size_t)BB * CC * NN;         // [4,8192,1024]

    ushort_t* hqHI  = (ushort_t*)d_ws;                 // 131072
    ushort_t* hqLO  = hqHI  + 131072;                  // 131072
    ushort_t* hkTH0 = hqLO  + 131072;                  // 524288
    ushort_t* hkTH1 = hkTH0 + 524288;                  // 524288
    ushort_t* hkTL0 = hkTH1 + 524288;                  // 524288
    ushort_t* hkTL1 = hkTL0 + 524288;                  // 524288
    ushort_t* hkDB  = hkTL1 + 524288;                  // 1048576
    float* inv  = (float*)(hkDB + 1048576);            // 4096 f32 (~7.5 MB total)

    k_pre<<<272, 256,  0, stream>>>(H, h, wq, wkv, hqHI, hqLO,
                                    hkTH0, hkTH1, hkTL0, hkTL1, hkDB);
    k_hv <<<256, 1024, 0, stream>>>(hqHI, hkTH0, hkTH1, hkDB, h, wo, inv, out0);
    k_att<<<256, 1024, 0, stream>>>(hqHI, hqLO, hkTH0, hkTH1, hkTL0, hkTL1, inv, att);
}